// Round 1
// baseline (306.657 us; speedup 1.0000x reference)
//
#include <hip/hip_runtime.h>
#include <stdint.h>

typedef __attribute__((ext_vector_type(4))) float f32x4;
typedef __attribute__((ext_vector_type(2))) float f32x2;
typedef __attribute__((ext_vector_type(8))) short bf16x8;

#define NB 4
#define NN 4096
#define CC 256

__device__ __forceinline__ unsigned short f2bf(float f) {
  union { float f; unsigned int u; } v; v.f = f;
  unsigned int u = v.u;
  return (unsigned short)((u + 0x7FFFu + ((u >> 16) & 1u)) >> 16);
}
__device__ __forceinline__ float bf2f(unsigned short h) {
  union { unsigned int u; float f; } v; v.u = ((unsigned int)h) << 16;
  return v.f;
}

// ---------------------------------------------------------------------------
// K1: projections. out = x @ W + b for W in {Wf, Wg, Wh}, stored bf16.
// grid = (256 row-tiles, 10 col-tiles): ct 0 -> f, 1 -> g, 2..9 -> hh cols.
// block tile: 64 rows x 32 cols, K = 256 in chunks of 64. xs stored [k][row].
// ---------------------------------------------------------------------------
__global__ __launch_bounds__(256) void k_proj(
    const float* __restrict__ x,
    const float* __restrict__ Wf, const float* __restrict__ bf_,
    const float* __restrict__ Wg, const float* __restrict__ bg_,
    const float* __restrict__ Wh, const float* __restrict__ bh_,
    unsigned short* __restrict__ fo, unsigned short* __restrict__ go,
    unsigned short* __restrict__ ho)
{
  __shared__ float xs[64][68];   // [k][row] transposed, pad 68
  __shared__ float ws[64][36];   // [k][col], pad 36

  const int t = threadIdx.x;
  const int rt = blockIdx.x, ct = blockIdx.y;
  const float* W; const float* bias; unsigned short* out; int nout, cbase;
  if (ct == 0)      { W = Wf; bias = bf_; out = fo; nout = 32;  cbase = 0; }
  else if (ct == 1) { W = Wg; bias = bg_; out = go; nout = 32;  cbase = 0; }
  else              { W = Wh; bias = bh_; out = ho; nout = 256; cbase = (ct - 2) * 32; }

  const int r0 = rt * 64;
  const int ty = t >> 4, tx = t & 15;
  float acc[4][2] = {{0.f,0.f},{0.f,0.f},{0.f,0.f},{0.f,0.f}};

  for (int k0 = 0; k0 < 256; k0 += 64) {
    __syncthreads();
    #pragma unroll
    for (int p = 0; p < 4; ++p) {           // x tile 64x64 f32, transposed into LDS
      int idx = t + (p << 8);
      int rr = idx >> 4, c4 = (idx & 15) << 2;
      f32x4 v = *(const f32x4*)&x[(size_t)(r0 + rr) * 256 + k0 + c4];
      xs[c4 + 0][rr] = v[0]; xs[c4 + 1][rr] = v[1];
      xs[c4 + 2][rr] = v[2]; xs[c4 + 3][rr] = v[3];
    }
    #pragma unroll
    for (int p = 0; p < 2; ++p) {           // W tile 64x32 f32
      int idx = t + (p << 8);
      int kk = idx >> 3, c4 = (idx & 7) << 2;
      *(f32x4*)&ws[kk][c4] = *(const f32x4*)&W[(size_t)(k0 + kk) * nout + cbase + c4];
    }
    __syncthreads();
    #pragma unroll 8
    for (int k = 0; k < 64; ++k) {
      f32x4 av = *(const f32x4*)&xs[k][ty * 4];
      f32x2 bv = *(const f32x2*)&ws[k][tx * 2];
      #pragma unroll
      for (int i = 0; i < 4; ++i) {
        acc[i][0] += av[i] * bv[0];
        acc[i][1] += av[i] * bv[1];
      }
    }
  }
  #pragma unroll
  for (int i = 0; i < 4; ++i) {
    #pragma unroll
    for (int j = 0; j < 2; ++j) {
      int c = cbase + tx * 2 + j;
      out[(size_t)(r0 + ty * 4 + i) * nout + c] = f2bf(acc[i][j] + bias[c]);
    }
  }
}

// ---------------------------------------------------------------------------
// K2: repack hh [b][n][256] bf16 into frag-ready V^T tiles:
// vT[b*64+tile][c*8 .. c*8+7] where c = dt*128 + s*64 + lane,
// element i of chunk = hh[n = tile*64 + 32*s + 8*(lane>>4) + i][d = dt*16 + (lane&15)].
// This makes PV B-fragment reads lane-linear (conflict-free ds_read_b128).
// grid = 256 blocks (b*64 + tile), 256 threads, 8 chunks each.
// ---------------------------------------------------------------------------
__global__ __launch_bounds__(256) void k_transpose(
    const unsigned short* __restrict__ hh, unsigned short* __restrict__ vT)
{
  const int bid = blockIdx.x;
  const int b = bid >> 6, tl = bid & 63;
  const unsigned short* src = hh + ((size_t)b * NN + tl * 64) * 256;
  unsigned short* dst = vT + (size_t)bid * (64 * 256);
  const int t = threadIdx.x;
  #pragma unroll
  for (int p = 0; p < 8; ++p) {
    int c = t + (p << 8);                 // 0..2047
    int dt = c >> 7, s = (c >> 6) & 1, l = c & 63;
    int h = l >> 4, q = l & 15;
    bf16x8 v;
    #pragma unroll
    for (int i = 0; i < 8; ++i)
      v[i] = (short)src[(size_t)(32 * s + 8 * h + i) * 256 + dt * 16 + q];
    *(bf16x8*)&dst[c * 8] = v;
  }
}

// ---------------------------------------------------------------------------
// K3: flash attention. 256 blocks (XCD-swizzled: each XCD serves one batch's
// K/V stream -> L2-resident). 4 waves x 16 queries, 64-key tiles.
// QK^T and PV via mfma_f32_16x16x32_bf16; online softmax; P through lane-
// linear LDS buffer (A-frag layout requires redistribution).
// attn (fp32, [b][n][256]) written into d_out as scratch.
// ---------------------------------------------------------------------------
__global__ __launch_bounds__(256) void k_attn(
    const unsigned short* __restrict__ fq,
    const unsigned short* __restrict__ gk,
    const unsigned short* __restrict__ vT,
    float* __restrict__ attn)
{
  __shared__ __align__(16) unsigned short g_r[2048];    // 4 KB  : QK B-frags
  __shared__ __align__(16) unsigned short v_r[16384];   // 32 KB : PV B-frags
  __shared__ __align__(16) unsigned short p_r[4096];    // 8 KB  : P A-frags (per wave 1024)

  const int bid = blockIdx.x;
  const int b  = (bid & 7) >> 1;                 // 2 XCDs per batch
  const int qt = (bid >> 3) + ((bid & 1) << 5);  // 64 q-tiles per batch
  const int t = threadIdx.x, w = t >> 6, l = t & 63;
  const int h = l >> 4, q = l & 15;
  const int qrow = qt * 64 + w * 16;

  // f A-frag: A[m = l&15][k = 8h+i] = f[qrow + q][8h + i]
  const bf16x8 afrag = *(const bf16x8*)&fq[((size_t)b * NN + qrow + q) * 32 + 8 * h];

  f32x4 acc[16];
  const f32x4 zero = {0.f, 0.f, 0.f, 0.f};
  #pragma unroll
  for (int dt = 0; dt < 16; ++dt) acc[dt] = zero;
  float mrow[4] = {-1e30f, -1e30f, -1e30f, -1e30f};
  float lrow[4] = {0.f, 0.f, 0.f, 0.f};

  for (int kt = 0; kt < 64; ++kt) {
    __syncthreads();   // previous tile's LDS reads complete
    // stage: 36 chunks of 1 KB (4 g + 32 v); wave w takes chunks [9w, 9w+9)
    #pragma unroll
    for (int p = 0; p < 9; ++p) {
      int c = w * 9 + p;
      if (c < 4) {
        const unsigned short* src =
            &gk[((size_t)b * NN + kt * 64 + c * 16 + q) * 32 + 8 * h];
        *(bf16x8*)&g_r[c * 512 + l * 8] = *(const bf16x8*)src;
      } else {
        int cv = c - 4;
        const unsigned short* src =
            &vT[((size_t)(b * 64 + kt)) * 16384 + cv * 512 + l * 8];
        *(bf16x8*)&v_r[cv * 512 + l * 8] = *(const bf16x8*)src;
      }
    }
    __syncthreads();

    // QK^T: S[16q][64k], 4 MFMAs
    f32x4 s[4];
    #pragma unroll
    for (int j = 0; j < 4; ++j) {
      bf16x8 bfrag = *(const bf16x8*)&g_r[j * 512 + l * 8];
      s[j] = __builtin_amdgcn_mfma_f32_16x16x32_bf16(afrag, bfrag, zero, 0, 0, 0);
    }

    // online softmax; lane holds rows (4h+i), keys (16j + q)
    float pt[4][4];
    #pragma unroll
    for (int i = 0; i < 4; ++i) {
      float mx = fmaxf(fmaxf(s[0][i], s[1][i]), fmaxf(s[2][i], s[3][i]));
      #pragma unroll
      for (int d = 1; d < 16; d <<= 1) mx = fmaxf(mx, __shfl_xor(mx, d));
      float mnew = fmaxf(mrow[i], mx);
      float scale = __expf(mrow[i] - mnew);
      mrow[i] = mnew;
      float ssum = 0.f;
      #pragma unroll
      for (int j = 0; j < 4; ++j) {
        float pv = __expf(s[j][i] - mnew);
        pt[j][i] = pv;
        ssum += pv;
      }
      #pragma unroll
      for (int d = 1; d < 16; d <<= 1) ssum += __shfl_xor(ssum, d);
      lrow[i] = lrow[i] * scale + ssum;
      #pragma unroll
      for (int dt = 0; dt < 16; ++dt) acc[dt][i] *= scale;
    }

    // scatter P into A-frag layout: element (row qq, key k) -> frag s_,
    // lane (((k&31)>>3)<<4)|qq, byte slot k&7
    #pragma unroll
    for (int j = 0; j < 4; ++j) {
      #pragma unroll
      for (int i = 0; i < 4; ++i) {
        int k = j * 16 + q;
        int s_ = k >> 5, h2 = (k & 31) >> 3, i2 = k & 7;
        p_r[w * 1024 + s_ * 512 + (h2 * 16 + (4 * h + i)) * 8 + i2] =
            f2bf(pt[j][i]);
      }
    }

    // PV: acc[16q][256d] += P[16q][64k] @ V[64k][256d]
    #pragma unroll
    for (int s_ = 0; s_ < 2; ++s_) {
      bf16x8 pa = *(const bf16x8*)&p_r[w * 1024 + s_ * 512 + l * 8];
      #pragma unroll
      for (int dt = 0; dt < 16; ++dt) {
        bf16x8 vb = *(const bf16x8*)&v_r[(dt * 2 + s_) * 512 + l * 8];
        acc[dt] = __builtin_amdgcn_mfma_f32_16x16x32_bf16(pa, vb, acc[dt], 0, 0, 0);
      }
    }
  }

  // normalize + store attn (D-frag: row = 4h+i, col = dt*16 + q)
  #pragma unroll
  for (int dt = 0; dt < 16; ++dt) {
    #pragma unroll
    for (int i = 0; i < 4; ++i) {
      attn[((size_t)b * NN + qrow + 4 * h + i) * 256 + dt * 16 + q] =
          acc[dt][i] / lrow[i];
    }
  }
}

// ---------------------------------------------------------------------------
// K4: o = attn @ Wo + bo; y = gamma*o + x. In-place on d_out (tile staged to
// LDS before overwrite). grid = 512 (32 rows each), 256 threads.
// ---------------------------------------------------------------------------
__global__ __launch_bounds__(256) void k_out(
    const float* __restrict__ Wo, const float* __restrict__ bo,
    const float* __restrict__ gamma, const float* __restrict__ x,
    float* __restrict__ y)
{
  __shared__ float at[32][260];               // attn tile fp32
  __shared__ __align__(16) unsigned short wo[64][264]; // Wo chunk bf16

  const int t = threadIdx.x;
  const int r0 = blockIdx.x * 32;

  #pragma unroll
  for (int p = 0; p < 8; ++p) {               // read own rows before overwrite
    int idx = t + (p << 8);
    int rr = idx >> 6, c4 = (idx & 63) << 2;
    *(f32x4*)&at[rr][c4] = *(const f32x4*)&y[(size_t)(r0 + rr) * 256 + c4];
  }

  const int ty = t >> 5, tx = t & 31;
  float acc[4][8];
  #pragma unroll
  for (int i = 0; i < 4; ++i)
    #pragma unroll
    for (int j = 0; j < 8; ++j) acc[i][j] = 0.f;

  for (int k0 = 0; k0 < 256; k0 += 64) {
    __syncthreads();
    #pragma unroll
    for (int p = 0; p < 8; ++p) {             // stage Wo chunk as bf16
      int idx = t + (p << 8);
      int kk = idx >> 5, c8 = (idx & 31) << 3;
      f32x4 w0 = *(const f32x4*)&Wo[(size_t)(k0 + kk) * 256 + c8];
      f32x4 w1 = *(const f32x4*)&Wo[(size_t)(k0 + kk) * 256 + c8 + 4];
      bf16x8 wv;
      #pragma unroll
      for (int ii = 0; ii < 4; ++ii) {
        wv[ii]     = (short)f2bf(w0[ii]);
        wv[ii + 4] = (short)f2bf(w1[ii]);
      }
      *(bf16x8*)&wo[kk][c8] = wv;
    }
    __syncthreads();
    #pragma unroll 4
    for (int k = 0; k < 64; ++k) {
      float a0 = at[ty * 4 + 0][k0 + k], a1 = at[ty * 4 + 1][k0 + k];
      float a2 = at[ty * 4 + 2][k0 + k], a3 = at[ty * 4 + 3][k0 + k];
      bf16x8 wv = *(const bf16x8*)&wo[k][tx * 8];
      #pragma unroll
      for (int j = 0; j < 8; ++j) {
        float bvj = bf2f((unsigned short)wv[j]);
        acc[0][j] += a0 * bvj; acc[1][j] += a1 * bvj;
        acc[2][j] += a2 * bvj; acc[3][j] += a3 * bvj;
      }
    }
  }

  const float gm = gamma[0];
  #pragma unroll
  for (int i = 0; i < 4; ++i) {
    #pragma unroll
    for (int j = 0; j < 8; ++j) {
      size_t off = (size_t)(r0 + ty * 4 + i) * 256 + tx * 8 + j;
      y[off] = gm * (acc[i][j] + bo[tx * 8 + j]) + x[off];
    }
  }
}

// ---------------------------------------------------------------------------
extern "C" void kernel_launch(void* const* d_in, const int* in_sizes, int n_in,
                              void* d_out, int out_size, void* d_ws, size_t ws_size,
                              hipStream_t stream) {
  const float* x     = (const float*)d_in[0];
  const float* Wf    = (const float*)d_in[1];
  const float* bf_   = (const float*)d_in[2];
  const float* Wg    = (const float*)d_in[3];
  const float* bg_   = (const float*)d_in[4];
  const float* Wh    = (const float*)d_in[5];
  const float* bh_   = (const float*)d_in[6];
  const float* Wo    = (const float*)d_in[7];
  const float* bo    = (const float*)d_in[8];
  const float* gamma = (const float*)d_in[9];

  // workspace layout (bf16): f 1MB | g 1MB | hh 8MB | vT 8MB  = 18 MB
  unsigned short* f  = (unsigned short*)d_ws;
  unsigned short* g  = f  + (size_t)16384 * 32;
  unsigned short* hh = g  + (size_t)16384 * 32;
  unsigned short* vT = hh + (size_t)16384 * 256;

  float* attn = (float*)d_out;   // d_out doubles as attn scratch, then y

  k_proj<<<dim3(256, 10), 256, 0, stream>>>(x, Wf, bf_, Wg, bg_, Wh, bh_, f, g, hh);
  k_transpose<<<256, 256, 0, stream>>>(hh, vT);
  k_attn<<<256, 256, 0, stream>>>(f, g, vT, attn);
  k_out<<<512, 256, 0, stream>>>(Wo, bo, gamma, x, attn);
}

// Round 2
// 306.341 us; speedup vs baseline: 1.0010x; 1.0010x over previous
//
#include <hip/hip_runtime.h>
#include <stdint.h>

typedef __attribute__((ext_vector_type(4))) float f32x4;
typedef __attribute__((ext_vector_type(2))) float f32x2;
typedef __attribute__((ext_vector_type(8))) short bf16x8;

#define NB 4
#define NN 4096
#define CC 256

__device__ __forceinline__ unsigned short f2bf(float f) {
  union { float f; unsigned int u; } v; v.f = f;
  unsigned int u = v.u;
  return (unsigned short)((u + 0x7FFFu + ((u >> 16) & 1u)) >> 16);
}
__device__ __forceinline__ float bf2f(unsigned short h) {
  union { unsigned int u; float f; } v; v.u = ((unsigned int)h) << 16;
  return v.f;
}

// ---------------------------------------------------------------------------
// K1: projections. out = x @ W + b for W in {Wf, Wg, Wh}, stored bf16.
// grid = (256 row-tiles, 10 col-tiles): ct 0 -> f, 1 -> g, 2..9 -> hh cols.
// block tile: 64 rows x 32 cols, K = 256 in chunks of 64. xs stored [k][row].
// ---------------------------------------------------------------------------
__global__ __launch_bounds__(256) void k_proj(
    const float* __restrict__ x,
    const float* __restrict__ Wf, const float* __restrict__ bf_,
    const float* __restrict__ Wg, const float* __restrict__ bg_,
    const float* __restrict__ Wh, const float* __restrict__ bh_,
    unsigned short* __restrict__ fo, unsigned short* __restrict__ go,
    unsigned short* __restrict__ ho)
{
  __shared__ float xs[64][68];   // [k][row] transposed, pad 68
  __shared__ float ws[64][36];   // [k][col], pad 36

  const int t = threadIdx.x;
  const int rt = blockIdx.x, ct = blockIdx.y;
  const float* W; const float* bias; unsigned short* out; int nout, cbase;
  if (ct == 0)      { W = Wf; bias = bf_; out = fo; nout = 32;  cbase = 0; }
  else if (ct == 1) { W = Wg; bias = bg_; out = go; nout = 32;  cbase = 0; }
  else              { W = Wh; bias = bh_; out = ho; nout = 256; cbase = (ct - 2) * 32; }

  const int r0 = rt * 64;
  const int ty = t >> 4, tx = t & 15;
  float acc[4][2] = {{0.f,0.f},{0.f,0.f},{0.f,0.f},{0.f,0.f}};

  for (int k0 = 0; k0 < 256; k0 += 64) {
    __syncthreads();
    #pragma unroll
    for (int p = 0; p < 4; ++p) {           // x tile 64x64 f32, transposed into LDS
      int idx = t + (p << 8);
      int rr = idx >> 4, c4 = (idx & 15) << 2;
      f32x4 v = *(const f32x4*)&x[(size_t)(r0 + rr) * 256 + k0 + c4];
      xs[c4 + 0][rr] = v[0]; xs[c4 + 1][rr] = v[1];
      xs[c4 + 2][rr] = v[2]; xs[c4 + 3][rr] = v[3];
    }
    #pragma unroll
    for (int p = 0; p < 2; ++p) {           // W tile 64x32 f32
      int idx = t + (p << 8);
      int kk = idx >> 3, c4 = (idx & 7) << 2;
      *(f32x4*)&ws[kk][c4] = *(const f32x4*)&W[(size_t)(k0 + kk) * nout + cbase + c4];
    }
    __syncthreads();
    #pragma unroll 8
    for (int k = 0; k < 64; ++k) {
      f32x4 av = *(const f32x4*)&xs[k][ty * 4];
      f32x2 bv = *(const f32x2*)&ws[k][tx * 2];
      #pragma unroll
      for (int i = 0; i < 4; ++i) {
        acc[i][0] += av[i] * bv[0];
        acc[i][1] += av[i] * bv[1];
      }
    }
  }
  #pragma unroll
  for (int i = 0; i < 4; ++i) {
    #pragma unroll
    for (int j = 0; j < 2; ++j) {
      int c = cbase + tx * 2 + j;
      out[(size_t)(r0 + ty * 4 + i) * nout + c] = f2bf(acc[i][j] + bias[c]);
    }
  }
}

// ---------------------------------------------------------------------------
// K2: repack hh [b][n][256] bf16 into frag-ready V^T tiles:
// vT[b*64+tile][c*8 .. c*8+7] where c = dt*128 + s*64 + lane,
// element i of chunk = hh[n = tile*64 + 32*s + 8*(lane>>4) + i][d = dt*16 + (lane&15)].
// This makes PV B-fragment reads lane-linear (conflict-free ds_read_b128).
// grid = 256 blocks (b*64 + tile), 256 threads, 8 chunks each.
// ---------------------------------------------------------------------------
__global__ __launch_bounds__(256) void k_transpose(
    const unsigned short* __restrict__ hh, unsigned short* __restrict__ vT)
{
  const int bid = blockIdx.x;
  const int b = bid >> 6, tl = bid & 63;
  const unsigned short* src = hh + ((size_t)b * NN + tl * 64) * 256;
  unsigned short* dst = vT + (size_t)bid * (64 * 256);
  const int t = threadIdx.x;
  #pragma unroll
  for (int p = 0; p < 8; ++p) {
    int c = t + (p << 8);                 // 0..2047
    int dt = c >> 7, s = (c >> 6) & 1, l = c & 63;
    int h = l >> 4, q = l & 15;
    bf16x8 v;
    #pragma unroll
    for (int i = 0; i < 8; ++i)
      v[i] = (short)src[(size_t)(32 * s + 8 * h + i) * 256 + dt * 16 + q];
    *(bf16x8*)&dst[c * 8] = v;
  }
}

// ---------------------------------------------------------------------------
// K3: flash attention. 256 blocks (XCD-swizzled: each XCD serves one batch's
// K/V stream -> L2-resident). 4 waves x 16 queries, 64-key tiles.
// QK^T and PV via mfma_f32_16x16x32_bf16; online softmax; P through lane-
// linear LDS buffer (A-frag layout requires redistribution).
// attn (fp32, [b][n][256]) written into d_out as scratch.
// ---------------------------------------------------------------------------
__global__ __launch_bounds__(256) void k_attn(
    const unsigned short* __restrict__ fq,
    const unsigned short* __restrict__ gk,
    const unsigned short* __restrict__ vT,
    float* __restrict__ attn)
{
  __shared__ __align__(16) unsigned short g_r[2048];    // 4 KB  : QK B-frags
  __shared__ __align__(16) unsigned short v_r[16384];   // 32 KB : PV B-frags
  __shared__ __align__(16) unsigned short p_r[4096];    // 8 KB  : P A-frags (per wave 1024)

  const int bid = blockIdx.x;
  const int b  = (bid & 7) >> 1;                 // 2 XCDs per batch
  const int qt = (bid >> 3) + ((bid & 1) << 5);  // 64 q-tiles per batch
  const int t = threadIdx.x, w = t >> 6, l = t & 63;
  const int h = l >> 4, q = l & 15;
  const int qrow = qt * 64 + w * 16;

  // f A-frag: A[m = l&15][k = 8h+i] = f[qrow + q][8h + i]
  const bf16x8 afrag = *(const bf16x8*)&fq[((size_t)b * NN + qrow + q) * 32 + 8 * h];

  f32x4 acc[16];
  const f32x4 zero = {0.f, 0.f, 0.f, 0.f};
  #pragma unroll
  for (int dt = 0; dt < 16; ++dt) acc[dt] = zero;
  float mrow[4] = {-1e30f, -1e30f, -1e30f, -1e30f};
  float lrow[4] = {0.f, 0.f, 0.f, 0.f};

  for (int kt = 0; kt < 64; ++kt) {
    __syncthreads();   // previous tile's LDS reads complete
    // stage: 36 chunks of 1 KB (4 g + 32 v); wave w takes chunks [9w, 9w+9)
    #pragma unroll
    for (int p = 0; p < 9; ++p) {
      int c = w * 9 + p;
      if (c < 4) {
        const unsigned short* src =
            &gk[((size_t)b * NN + kt * 64 + c * 16 + q) * 32 + 8 * h];
        *(bf16x8*)&g_r[c * 512 + l * 8] = *(const bf16x8*)src;
      } else {
        int cv = c - 4;
        const unsigned short* src =
            &vT[((size_t)(b * 64 + kt)) * 16384 + cv * 512 + l * 8];
        *(bf16x8*)&v_r[cv * 512 + l * 8] = *(const bf16x8*)src;
      }
    }
    __syncthreads();

    // QK^T: S[16q][64k], 4 MFMAs
    f32x4 s[4];
    #pragma unroll
    for (int j = 0; j < 4; ++j) {
      bf16x8 bfrag = *(const bf16x8*)&g_r[j * 512 + l * 8];
      s[j] = __builtin_amdgcn_mfma_f32_16x16x32_bf16(afrag, bfrag, zero, 0, 0, 0);
    }

    // online softmax; lane holds rows (4h+i), keys (16j + q)
    float pt[4][4];
    #pragma unroll
    for (int i = 0; i < 4; ++i) {
      float mx = fmaxf(fmaxf(s[0][i], s[1][i]), fmaxf(s[2][i], s[3][i]));
      #pragma unroll
      for (int d = 1; d < 16; d <<= 1) mx = fmaxf(mx, __shfl_xor(mx, d));
      float mnew = fmaxf(mrow[i], mx);
      float scale = __expf(mrow[i] - mnew);
      mrow[i] = mnew;
      float ssum = 0.f;
      #pragma unroll
      for (int j = 0; j < 4; ++j) {
        float pv = __expf(s[j][i] - mnew);
        pt[j][i] = pv;
        ssum += pv;
      }
      #pragma unroll
      for (int d = 1; d < 16; d <<= 1) ssum += __shfl_xor(ssum, d);
      lrow[i] = lrow[i] * scale + ssum;
      #pragma unroll
      for (int dt = 0; dt < 16; ++dt) acc[dt][i] *= scale;
    }

    // scatter P into A-frag layout: element (row qq, key k) -> frag s_,
    // lane (((k&31)>>3)<<4)|qq, byte slot k&7
    #pragma unroll
    for (int j = 0; j < 4; ++j) {
      #pragma unroll
      for (int i = 0; i < 4; ++i) {
        int k = j * 16 + q;
        int s_ = k >> 5, h2 = (k & 31) >> 3, i2 = k & 7;
        p_r[w * 1024 + s_ * 512 + (h2 * 16 + (4 * h + i)) * 8 + i2] =
            f2bf(pt[j][i]);
      }
    }

    // PV: acc[16q][256d] += P[16q][64k] @ V[64k][256d]
    #pragma unroll
    for (int s_ = 0; s_ < 2; ++s_) {
      bf16x8 pa = *(const bf16x8*)&p_r[w * 1024 + s_ * 512 + l * 8];
      #pragma unroll
      for (int dt = 0; dt < 16; ++dt) {
        bf16x8 vb = *(const bf16x8*)&v_r[(dt * 2 + s_) * 512 + l * 8];
        acc[dt] = __builtin_amdgcn_mfma_f32_16x16x32_bf16(pa, vb, acc[dt], 0, 0, 0);
      }
    }
  }

  // normalize + store attn (D-frag: row = 4h+i, col = dt*16 + q)
  #pragma unroll
  for (int dt = 0; dt < 16; ++dt) {
    #pragma unroll
    for (int i = 0; i < 4; ++i) {
      attn[((size_t)b * NN + qrow + 4 * h + i) * 256 + dt * 16 + q] =
          acc[dt][i] / lrow[i];
    }
  }
}

// ---------------------------------------------------------------------------
// K4: o = attn @ Wo + bo; y = gamma*o + x. In-place on d_out (tile staged to
// LDS before overwrite). grid = 512 (32 rows each), 256 threads.
// ---------------------------------------------------------------------------
__global__ __launch_bounds__(256) void k_out(
    const float* __restrict__ Wo, const float* __restrict__ bo,
    const float* __restrict__ gamma, const float* __restrict__ x,
    float* __restrict__ y)
{
  __shared__ float at[32][260];               // attn tile fp32
  __shared__ __align__(16) unsigned short wo[64][264]; // Wo chunk bf16

  const int t = threadIdx.x;
  const int r0 = blockIdx.x * 32;

  #pragma unroll
  for (int p = 0; p < 8; ++p) {               // read own rows before overwrite
    int idx = t + (p << 8);
    int rr = idx >> 6, c4 = (idx & 63) << 2;
    *(f32x4*)&at[rr][c4] = *(const f32x4*)&y[(size_t)(r0 + rr) * 256 + c4];
  }

  const int ty = t >> 5, tx = t & 31;
  float acc[4][8];
  #pragma unroll
  for (int i = 0; i < 4; ++i)
    #pragma unroll
    for (int j = 0; j < 8; ++j) acc[i][j] = 0.f;

  for (int k0 = 0; k0 < 256; k0 += 64) {
    __syncthreads();
    #pragma unroll
    for (int p = 0; p < 8; ++p) {             // stage Wo chunk as bf16
      int idx = t + (p << 8);
      int kk = idx >> 5, c8 = (idx & 31) << 3;
      f32x4 w0 = *(const f32x4*)&Wo[(size_t)(k0 + kk) * 256 + c8];
      f32x4 w1 = *(const f32x4*)&Wo[(size_t)(k0 + kk) * 256 + c8 + 4];
      bf16x8 wv;
      #pragma unroll
      for (int ii = 0; ii < 4; ++ii) {
        wv[ii]     = (short)f2bf(w0[ii]);
        wv[ii + 4] = (short)f2bf(w1[ii]);
      }
      *(bf16x8*)&wo[kk][c8] = wv;
    }
    __syncthreads();
    #pragma unroll 4
    for (int k = 0; k < 64; ++k) {
      float a0 = at[ty * 4 + 0][k0 + k], a1 = at[ty * 4 + 1][k0 + k];
      float a2 = at[ty * 4 + 2][k0 + k], a3 = at[ty * 4 + 3][k0 + k];
      bf16x8 wv = *(const bf16x8*)&wo[k][tx * 8];
      #pragma unroll
      for (int j = 0; j < 8; ++j) {
        float bvj = bf2f((unsigned short)wv[j]);
        acc[0][j] += a0 * bvj; acc[1][j] += a1 * bvj;
        acc[2][j] += a2 * bvj; acc[3][j] += a3 * bvj;
      }
    }
  }

  const float gm = gamma[0];
  #pragma unroll
  for (int i = 0; i < 4; ++i) {
    #pragma unroll
    for (int j = 0; j < 8; ++j) {
      size_t off = (size_t)(r0 + ty * 4 + i) * 256 + tx * 8 + j;
      y[off] = gm * (acc[i][j] + bo[tx * 8 + j]) + x[off];
    }
  }
}

// ---------------------------------------------------------------------------
extern "C" void kernel_launch(void* const* d_in, const int* in_sizes, int n_in,
                              void* d_out, int out_size, void* d_ws, size_t ws_size,
                              hipStream_t stream) {
  const float* x     = (const float*)d_in[0];
  const float* Wf    = (const float*)d_in[1];
  const float* bf_   = (const float*)d_in[2];
  const float* Wg    = (const float*)d_in[3];
  const float* bg_   = (const float*)d_in[4];
  const float* Wh    = (const float*)d_in[5];
  const float* bh_   = (const float*)d_in[6];
  const float* Wo    = (const float*)d_in[7];
  const float* bo    = (const float*)d_in[8];
  const float* gamma = (const float*)d_in[9];

  // workspace layout (bf16): f 1MB | g 1MB | hh 8MB | vT 8MB  = 18 MB
  unsigned short* f  = (unsigned short*)d_ws;
  unsigned short* g  = f  + (size_t)16384 * 32;
  unsigned short* hh = g  + (size_t)16384 * 32;
  unsigned short* vT = hh + (size_t)16384 * 256;

  float* attn = (float*)d_out;   // d_out doubles as attn scratch, then y

  k_proj<<<dim3(256, 10), 256, 0, stream>>>(x, Wf, bf_, Wg, bg_, Wh, bh_, f, g, hh);
  k_transpose<<<256, 256, 0, stream>>>(hh, vT);
  k_attn<<<256, 256, 0, stream>>>(f, g, vT, attn);
  k_out<<<512, 256, 0, stream>>>(Wo, bo, gamma, x, attn);
}